// Round 13
// baseline (293.525 us; speedup 1.0000x reference)
//
#include <hip/hip_runtime.h>

#define BB 4
#define NN 2048
#define CIN 256
#define HH 8
#define COUT 256
#define LOG2E 1.44269504088896340736f

// proj tiling: 128x64 tile, 4x4 micro, 512 threads, KT=16, double-buffered.
#define PBM 128
#define PBN 64
#define PKT 16
#define NKT (CIN / PKT)
// attn tiling: 8 rows/block, 64-col chunks, full j-range per block.
#define TI 8
#define CJ 64
#define NC (NN / CJ)

// ---------------- Kernel 1: h = x@W + b, fused lf/ls (transposed, xlog2e) ---
// 256 blocks x 512 threads (8 waves = 2/SIMD: TLP to hide LDS/L2 latency,
// which R12's 1-wave/SIMD config lacked).
__global__ __launch_bounds__(512) void gat_proj(
    const float* __restrict__ x, const float* __restrict__ W,
    const float* __restrict__ bias, const float* __restrict__ afst,
    const float* __restrict__ asnd, float* __restrict__ hout,
    float* __restrict__ lfT, float* __restrict__ lsT)
{
    __shared__ float xsT[2][PKT][PBM + 4];   // [buf][k][row]
    __shared__ float wls[2][PKT][PBN + 4];   // [buf][k][col]
    const int t = threadIdx.x;
    const int bx = blockIdx.x & 3;           // col tile (2 heads)
    const int by = blockIdx.x >> 2;          // row tile
    const int row0 = by * PBM, col0 = bx * PBN;
    const int tx = t & 15, ty = t >> 4;      // 16 col-groups x4, 32 row-groups x4

    // staging: x 128x16 -> 1 float4/thread (transposed store); W 16x64 -> t<256
    const int srow = t >> 2, skq = (t & 3) * 4;
    const float* xb = x + (size_t)(row0 + srow) * CIN + skq;
    const int swk = t >> 4, swc = (t & 15) * 4;
    const float* wb = W + (size_t)swk * COUT + col0 + swc;

    float4 xr = *(const float4*)xb;
    float4 wr;
    if (t < 256) wr = *(const float4*)wb;
    xsT[0][skq+0][srow] = xr.x; xsT[0][skq+1][srow] = xr.y;
    xsT[0][skq+2][srow] = xr.z; xsT[0][skq+3][srow] = xr.w;
    if (t < 256) *(float4*)&wls[0][swk][swc] = wr;
    __syncthreads();

    float acc[4][4];
#pragma unroll
    for (int i = 0; i < 4; ++i)
#pragma unroll
        for (int j = 0; j < 4; ++j) acc[i][j] = 0.f;

    for (int kt = 0; kt < NKT; ++kt) {
        if (kt + 1 < NKT) {                  // issue next-tile loads early
            xr = *(const float4*)(xb + (kt + 1) * PKT);
            if (t < 256) wr = *(const float4*)(wb + (size_t)(kt + 1) * PKT * COUT);
        }
        const int cur = kt & 1;
#pragma unroll
        for (int k = 0; k < PKT; ++k) {
            const float4 xv = *(const float4*)&xsT[cur][k][ty * 4];  // phase-bcast
            const float4 wv = *(const float4*)&wls[cur][k][tx * 4];  // 2-way free
            acc[0][0]=fmaf(xv.x,wv.x,acc[0][0]); acc[0][1]=fmaf(xv.x,wv.y,acc[0][1]);
            acc[0][2]=fmaf(xv.x,wv.z,acc[0][2]); acc[0][3]=fmaf(xv.x,wv.w,acc[0][3]);
            acc[1][0]=fmaf(xv.y,wv.x,acc[1][0]); acc[1][1]=fmaf(xv.y,wv.y,acc[1][1]);
            acc[1][2]=fmaf(xv.y,wv.z,acc[1][2]); acc[1][3]=fmaf(xv.y,wv.w,acc[1][3]);
            acc[2][0]=fmaf(xv.z,wv.x,acc[2][0]); acc[2][1]=fmaf(xv.z,wv.y,acc[2][1]);
            acc[2][2]=fmaf(xv.z,wv.z,acc[2][2]); acc[2][3]=fmaf(xv.z,wv.w,acc[2][3]);
            acc[3][0]=fmaf(xv.w,wv.x,acc[3][0]); acc[3][1]=fmaf(xv.w,wv.y,acc[3][1]);
            acc[3][2]=fmaf(xv.w,wv.z,acc[3][2]); acc[3][3]=fmaf(xv.w,wv.w,acc[3][3]);
        }
        __syncthreads();
        if (kt + 1 < NKT) {                  // commit next buffer (latency hidden)
            const int nxt = cur ^ 1;
            xsT[nxt][skq+0][srow] = xr.x; xsT[nxt][skq+1][srow] = xr.y;
            xsT[nxt][skq+2][srow] = xr.z; xsT[nxt][skq+3][srow] = xr.w;
            if (t < 256) *(float4*)&wls[nxt][swk][swc] = wr;
            __syncthreads();
        }
    }

    // epilogue: +bias, store h, fused lf/ls (head = 32 cols = 8 tx lanes)
    const float4 bv = *(const float4*)(bias + col0 + tx * 4);
    const float4 af = *(const float4*)(afst + col0 + tx * 4);
    const float4 as = *(const float4*)(asnd + col0 + tx * 4);
    const int hd = (col0 + tx * 4) >> 5;
#pragma unroll
    for (int i = 0; i < 4; ++i) {
        float4 o;
        o.x = acc[i][0] + bv.x; o.y = acc[i][1] + bv.y;
        o.z = acc[i][2] + bv.z; o.w = acc[i][3] + bv.w;
        const int row = row0 + ty * 4 + i;
        *(float4*)(hout + (size_t)row * COUT + col0 + tx * 4) = o;
        float pf = o.x * af.x + o.y * af.y + o.z * af.z + o.w * af.w;
        float ps = o.x * as.x + o.y * as.y + o.z * as.z + o.w * as.w;
        pf += __shfl_xor(pf, 1); ps += __shfl_xor(ps, 1);
        pf += __shfl_xor(pf, 2); ps += __shfl_xor(ps, 2);
        pf += __shfl_xor(pf, 4); ps += __shfl_xor(ps, 4);
        if ((tx & 7) == 0) {
            const int b = row >> 11, n = row & (NN - 1);
            lfT[(size_t)(b * HH + hd) * NN + n] = pf * LOG2E;  // pre-scale for exp2
            lsT[(size_t)(b * HH + hd) * NN + n] = ps * LOG2E;
        }
    }
}

// e-tile word offset, layout [jl][slot]; slot'=((h<<1)+half)^(jl&7).
// Quarter-phase analysis: writes (16 lanes: 8 slots x 2 rows) and reads
// (16 lanes: <=4 distinct addrs, broadcast) both conflict-free. (R4/R12: 0.)
__device__ __forceinline__ int eoff4(int jl, int h, int half) {
    return jl * 64 + ((((h << 1) + half) ^ (jl & 7)) << 2);
}

// ---------------- Kernel 2: fused mask+leaky+exp softmax / PV --------------
// One block = (b, 8 rows), grid 1024. e-phase unchanged (one exp per
// (b,i,j,h)). PV remapped: wave pass covers 2 jl; lane = (jl-half l5,
// head ph, channel-octet oct) -> 8x8 accumulators/thread. Each e-b128 read
// now feeds 64 FMA (was 32): LDS instrs 36->20 per chunk per thread.
__global__ __launch_bounds__(256) void gat_attn(
    const int* __restrict__ G, const float* __restrict__ hin,
    const float* __restrict__ lfT, const float* __restrict__ lsT,
    float* __restrict__ out)
{
    __shared__ __align__(16) float e_lds[CJ * 64];   // 16KB; reused as buf
    __shared__ unsigned g_lds[4][CJ];
    __shared__ float s_lds[TI][HH];

    const int t = threadIdx.x;
    const int b = blockIdx.x >> 8;
    const int i0 = (blockIdx.x & 255) * TI;
    const int h = t >> 5, jj = t & 31;    // e-phase mapping
    const int w = t >> 6, l = t & 63;     // PV mapping
    const int l5 = l >> 5;                // which jl of the pass
    const int ph = (l >> 2) & 7;          // PV head
    const int ch0 = ph * 32 + (l & 3) * 8;  // channel-octet base

    const float* lsrow = lsT + (size_t)(b * HH + h) * NN;
    float lfv[TI];
#pragma unroll
    for (int r = 0; r < TI; ++r)
        lfv[r] = lfT[(size_t)(b * HH + h) * NN + i0 + r];

    float sp[TI];
    float a[8][8];
#pragma unroll
    for (int r = 0; r < 8; ++r) {
        sp[r] = 0.f;
#pragma unroll
        for (int cc = 0; cc < 8; ++cc) a[r][cc] = 0.f;
    }

    // prefetch chunk 0: G rows 2w,2w+1 at col l; lsT at (h, jj/jj+32)
    const int* gbase = G + ((size_t)b * NN + i0 + 2 * w) * NN + l;
    int g0 = gbase[0], g1 = gbase[NN];
    float ls0 = lsrow[jj], ls1 = lsrow[32 + jj];

    for (int c = 0; c < NC; ++c) {
        const int j0 = c * CJ;
        g_lds[w][l] = (g0 ? 1u : 0u) | (g1 ? 2u : 0u);   // commit prefetched G
        __syncthreads();
        // e = G ? exp2(max(s,0.2s)) : 0 (s pre-scaled by log2e)
        {
            const unsigned gmA = g_lds[0][jj] | (g_lds[1][jj] << 2) |
                                 (g_lds[2][jj] << 4) | (g_lds[3][jj] << 6);
            const unsigned gmB = g_lds[0][jj+32] | (g_lds[1][jj+32] << 2) |
                                 (g_lds[2][jj+32] << 4) | (g_lds[3][jj+32] << 6);
            float ev[TI];
#pragma unroll
            for (int r = 0; r < TI; ++r) {
                float s = lfv[r] + ls0;
                s = fmaxf(s, 0.2f * s);
                ev[r] = ((gmA >> r) & 1u) ? exp2f(s) : 0.f;
                sp[r] += ev[r];
            }
            *(float4*)&e_lds[eoff4(jj, h, 0)] = make_float4(ev[0], ev[1], ev[2], ev[3]);
            *(float4*)&e_lds[eoff4(jj, h, 1)] = make_float4(ev[4], ev[5], ev[6], ev[7]);
#pragma unroll
            for (int r = 0; r < TI; ++r) {
                float s = lfv[r] + ls1;
                s = fmaxf(s, 0.2f * s);
                ev[r] = ((gmB >> r) & 1u) ? exp2f(s) : 0.f;
                sp[r] += ev[r];
            }
            *(float4*)&e_lds[eoff4(jj+32, h, 0)] = make_float4(ev[0], ev[1], ev[2], ev[3]);
            *(float4*)&e_lds[eoff4(jj+32, h, 1)] = make_float4(ev[4], ev[5], ev[6], ev[7]);
        }
        __syncthreads();
        // issue next chunk's G + lsT loads (consumed after next barrier)
        if (c + 1 < NC) {
            const int* gp = gbase + (size_t)(j0 + CJ);
            g0 = gp[0]; g1 = gp[NN];
            ls0 = lsrow[j0 + CJ + jj]; ls1 = lsrow[j0 + CJ + 32 + jj];
        }
        // PV: 8 passes of 2 jl; thread covers (8 rows x its 8 channels)
        {
            const float* hb = hin + ((size_t)b * NN + j0 + w + 4 * l5) * COUT + ch0;
            float4 hA = *(const float4*)hb;
            float4 hB = *(const float4*)(hb + 4);
#pragma unroll
            for (int p = 0; p < 8; ++p) {
                const int jl = w + 8 * p + 4 * l5;
                const float4 lo = *(const float4*)&e_lds[eoff4(jl, ph, 0)];
                const float4 hi = *(const float4*)&e_lds[eoff4(jl, ph, 1)];
                float4 hA2, hB2;
                if (p < 7) {
                    hA2 = *(const float4*)(hb + (size_t)(p + 1) * 8 * COUT);
                    hB2 = *(const float4*)(hb + (size_t)(p + 1) * 8 * COUT + 4);
                }
#define PV8(ER, EV) \
    a[ER][0]=fmaf(EV,hA.x,a[ER][0]); a[ER][1]=fmaf(EV,hA.y,a[ER][1]); \
    a[ER][2]=fmaf(EV,hA.z,a[ER][2]); a[ER][3]=fmaf(EV,hA.w,a[ER][3]); \
    a[ER][4]=fmaf(EV,hB.x,a[ER][4]); a[ER][5]=fmaf(EV,hB.y,a[ER][5]); \
    a[ER][6]=fmaf(EV,hB.z,a[ER][6]); a[ER][7]=fmaf(EV,hB.w,a[ER][7]);
                PV8(0, lo.x) PV8(1, lo.y) PV8(2, lo.z) PV8(3, lo.w)
                PV8(4, hi.x) PV8(5, hi.y) PV8(6, hi.z) PV8(7, hi.w)
#undef PV8
                hA = hA2; hB = hB2;
            }
        }
        __syncthreads();
    }
    // softmax denominators: reduce across the 32 jj-lanes of each head
#pragma unroll
    for (int off = 16; off; off >>= 1) {
#pragma unroll
        for (int r = 0; r < TI; ++r) sp[r] += __shfl_xor(sp[r], off);
    }
    if (jj == 0) {
#pragma unroll
        for (int r = 0; r < TI; ++r) s_lds[r][h] = sp[r];
    }
    // fold jl-half partials (lane +-32), then cross-wave reduce via e_lds
#pragma unroll
    for (int r = 0; r < 8; ++r)
#pragma unroll
        for (int cc = 0; cc < 8; ++cc)
            a[r][cc] += __shfl_xor(a[r][cc], 32);
    float* buf = e_lds;                   // [2 waves][64 vals][32 lanes]
    if (w >= 2 && l < 32) {
#pragma unroll
        for (int r = 0; r < 8; ++r)
#pragma unroll
            for (int cc = 0; cc < 8; ++cc)
                buf[((w - 2) << 11) + ((r * 8 + cc) << 5) + l] = a[r][cc];
    }
    __syncthreads();
    if (w < 2 && l < 32) {
#pragma unroll
        for (int r = 0; r < 8; ++r)
#pragma unroll
            for (int cc = 0; cc < 8; ++cc)
                a[r][cc] += buf[(w << 11) + ((r * 8 + cc) << 5) + l];
    }
    __syncthreads();
    if (w == 1 && l < 32) {
#pragma unroll
        for (int r = 0; r < 8; ++r)
#pragma unroll
            for (int cc = 0; cc < 8; ++cc)
                buf[((r * 8 + cc) << 5) + l] = a[r][cc];
    }
    __syncthreads();
    if (w == 0 && l < 32) {
#pragma unroll
        for (int r = 0; r < 8; ++r) {
            const float inv = 1.f / s_lds[r][ph];
            float4 o1, o2;
            o1.x = (a[r][0] + buf[((r * 8 + 0) << 5) + l]) * inv;
            o1.y = (a[r][1] + buf[((r * 8 + 1) << 5) + l]) * inv;
            o1.z = (a[r][2] + buf[((r * 8 + 2) << 5) + l]) * inv;
            o1.w = (a[r][3] + buf[((r * 8 + 3) << 5) + l]) * inv;
            o2.x = (a[r][4] + buf[((r * 8 + 4) << 5) + l]) * inv;
            o2.y = (a[r][5] + buf[((r * 8 + 5) << 5) + l]) * inv;
            o2.z = (a[r][6] + buf[((r * 8 + 6) << 5) + l]) * inv;
            o2.w = (a[r][7] + buf[((r * 8 + 7) << 5) + l]) * inv;
            float* op = out + (size_t)(b * NN + i0 + r) * COUT + ch0;
            *(float4*)op = o1;
            *(float4*)(op + 4) = o2;
        }
    }
}

extern "C" void kernel_launch(void* const* d_in, const int* in_sizes, int n_in,
                              void* d_out, int out_size, void* d_ws, size_t ws_size,
                              hipStream_t stream) {
    const float* x    = (const float*)d_in[0];
    const int*   G    = (const int*)d_in[1];
    const float* W    = (const float*)d_in[2];
    const float* bias = (const float*)d_in[3];
    const float* afst = (const float*)d_in[4];
    const float* asnd = (const float*)d_in[5];
    float* out = (float*)d_out;

    // ws: h 8MB | lfT 256KB | lsT 256KB
    float* h_ws   = (float*)d_ws;
    float* lfT_ws = h_ws + (size_t)BB * NN * COUT;
    float* lsT_ws = lfT_ws + (size_t)BB * HH * NN;

    hipLaunchKernelGGL(gat_proj, dim3((BB * NN / PBM) * (COUT / PBN)), dim3(512),
                       0, stream, x, W, bias, afst, asnd, h_ws, lfT_ws, lsT_ws);
    hipLaunchKernelGGL(gat_attn, dim3(BB * (NN / TI)), dim3(256), 0, stream,
                       G, h_ws, lfT_ws, lsT_ws, out);
}